// Round 8
// baseline (575.190 us; speedup 1.0000x reference)
//
#include <hip/hip_runtime.h>
#include <stdint.h>

#define E_TOTAL 160000
#define NODES   10000
#define FDIM    128
#define HDIM    128
#define WN      1024
#define CDIM    64
#define EPB     32
#define NTHR    256
#define GPB     4        // groups (32 edges) per persistent block
#define NBLK    1250     // 1250 * 4 * 32 = 160000

typedef __bf16 bf16x8 __attribute__((ext_vector_type(8)));
typedef __bf16 bf16x4 __attribute__((ext_vector_type(4)));
typedef float  f32x4  __attribute__((ext_vector_type(4)));

#define MFMA16(a,b,c) __builtin_amdgcn_mfma_f32_16x16x32_bf16(a,b,c,0,0,0)

// ws layout: [0, 256K) W2B bf16 B-frags ; [512K, 544K) W1B ; [576K, +40K) cnt
#define WS_W1B (512*1024)
#define WS_CNT (576*1024)

__device__ __forceinline__ f32x4 ntload4(const float* p) {
    return __builtin_nontemporal_load((const f32x4*)p);
}

// ---------- prep: W1/W2 -> bf16 B-fragments + zero out/cnt ----------
// Frag layout: [tile][ks][lane][8 bf16]; lane: n = tile*16+(lane&15), k = ks*32+(lane>>4)*8+j.
__global__ void prep_kernel(const float* __restrict__ W1, const float* __restrict__ W2,
                            __bf16* __restrict__ W1B, __bf16* __restrict__ W2B,
                            float* __restrict__ out_acc, int* __restrict__ cnt) {
    const int b   = blockIdx.x;
    const int tid = threadIdx.x;
    if (b < 72) {
        const float* W = (b < 64) ? W2 : W1;
        __bf16* outB   = (b < 64) ? W2B : W1B;
        const int N    = (b < 64) ? WN : HDIM;
        const int tile = (b < 64) ? b : (b - 64);
        const int lane = tid & 63, ks = tid >> 6;
        const int n  = tile * 16 + (lane & 15);
        const int k0 = ks * 32 + (lane >> 4) * 8;
        bf16x8 hi;
        #pragma unroll
        for (int j = 0; j < 8; ++j) hi[j] = (__bf16)W[(size_t)(k0 + j) * N + n];
        *(bf16x8*)(outB + ((size_t)(tile * 4 + ks) * 64 + lane) * 8) = hi;
    } else {
        const int zt     = (b - 72) * NTHR + tid;
        const int stride = ((int)gridDim.x - 72) * NTHR;
        const float4 z4 = make_float4(0.f, 0.f, 0.f, 0.f);
        for (int i = zt; i < NODES * CDIM / 4; i += stride) ((float4*)out_acc)[i] = z4;
        for (int i = zt; i < NODES; i += stride) cnt[i] = 0;
    }
}

// ---------- fused: persistent-lite; r3-proven per-group core ----------
// 32 edges/group, 4 waves = (th, kh); GPB=4 groups per block.
// r5 (ILP depth) and r7 (B-frag reuse / L2 traffic) both NULL -> structure
// is latency/stall-bound in ways those levers don't touch. This round only
// amortizes per-block setup (b2s staging, Wp) + end-of-kernel atomic drain
// over 4 groups. NO loop-carried register state (r1/r4/r6 spill rule: ~30
// spare regs max; every per-group load is issued inside the loop body).
// LDS arena 25152 B (r3 layout):
//   [0,8192)      s_attr == s_h (aliased; barrier B1.5 guards alias)
//   [8192,20480)  s_f [6][16][32] f32
//   [20480,24576) s_b2s   (staged once; outside zA/zB overlay)
//   [24576,25008) s_sh1 [3][36]
//   [25024,25152) s_dst
//   tail: zA [0,8704), zB [8704,17408)  (ZS=68 rows; B0 guards reuse)
// Scatter: one FULL edge row (64 contiguous floats) per atomic instruction ->
// 4 fully-covered 64B lines/instr (proven r3: WRITE_SIZE 325->45 MB).
#define ZS 68
__global__ __launch_bounds__(NTHR, 4)
void fused_edge_kernel(const float* __restrict__ x,
                       const int*   __restrict__ edge_index,
                       const float* __restrict__ edge_attr,
                       const float* __restrict__ edge_sh,
                       const float* __restrict__ fc_b1,
                       const float* __restrict__ fc_b2,
                       const __bf16* __restrict__ W1B,
                       const __bf16* __restrict__ W2B,
                       float* __restrict__ out_acc,
                       int*   __restrict__ cnt)
{
    __shared__ __align__(16) char s_arena[25152];
    __bf16* s_attr = (__bf16*)s_arena;
    __bf16* s_h    = (__bf16*)s_arena;                 // aliased with s_attr
    float (*s_f)[16][32] = (float (*)[16][32])(s_arena + 8192);
    float*  s_b2s  = (float*)(s_arena + 20480);
    float (*s_sh1)[36] = (float (*)[36])(s_arena + 24576);
    int*    s_dst  = (int*)(s_arena + 25024);

    const int tid  = threadIdx.x;
    const int w    = tid >> 6;
    const int th   = w >> 1;
    const int kh   = w & 1;
    const int lane = tid & 63;
    const int quad = lane >> 4;
    const int li   = lane & 15;

    // once per block: stage fc_b2 (first read after group-0 B1) + GEMM2 base
    *(f32x4*)&s_b2s[tid * 4] = *(const f32x4*)(fc_b2 + tid * 4);
    const int tbase = th * 32;
    const __bf16* Wp = W2B + ((size_t)(tbase * 4 + kh * 2) * 64 + lane) * 8;

    for (int j = 0; j < GPB; ++j) {
        const int e0 = (blockIdx.x * GPB + j) * EPB;
        if (j > 0) __syncthreads();   // B0: prior scatter's zA/zB reads done

        // ---- phase 0a: geometry factors (wave w, lanes<32: u in [w*4,+4)) ----
        if (lane < 32) {
            const int e  = lane;
            const int up = w * 4;
            const int ge = e0 + e;
            const int src = edge_index[ge];
            const f32x4 sh4 = ntload4(edge_sh + (size_t)ge * 4);
            if (tid < EPB) {
                const int d = edge_index[E_TOTAL + ge];
                s_dst[e] = d;
                atomicAdd(&cnt[d], 1);
                s_sh1[0][e] = sh4.y; s_sh1[1][e] = sh4.z; s_sh1[2][e] = sh4.w;
            }
            const float* xp = x + (size_t)src * CDIM;
            const float4 x0v = *(const float4*)(xp + up);
            const float4 xa  = *(const float4*)(xp + 16 + up * 3);
            const float4 xb  = *(const float4*)(xp + 16 + up * 3 + 4);
            const float4 xc  = *(const float4*)(xp + 16 + up * 3 + 8);
            const float x1v[4][3] = {
                {xa.x, xa.y, xa.z}, {xa.w, xb.x, xb.y},
                {xb.z, xb.w, xc.x}, {xc.y, xc.z, xc.w}};
            const float x0a[4] = {x0v.x, x0v.y, x0v.z, x0v.w};
            const float alpha = 0.17677669529663689f;           // 1/sqrt(2*MUL)
            const float ai3   = alpha * 0.57735026918962576f;   // alpha/sqrt(3)
            const float sh0 = sh4.x;
            #pragma unroll
            for (int jj = 0; jj < 4; ++jj) {
                const int u = up + jj;
                const float x0u = x0a[jj];
                s_f[0][u][e] = alpha * sh0 * x0u;
                s_f[1][u][e] = alpha * x0u;
                s_f[2][u][e] = alpha * sh0 * x1v[jj][0];
                s_f[3][u][e] = alpha * sh0 * x1v[jj][1];
                s_f[4][u][e] = alpha * sh0 * x1v[jj][2];
                s_f[5][u][e] = ai3 * (x1v[jj][0]*sh4.y + x1v[jj][1]*sh4.z + x1v[jj][2]*sh4.w);
            }
        }
        // ---- phase 0b: attr -> fragment-direct bf16 LDS ----
        #pragma unroll
        for (int t4 = 0; t4 < 4; ++t4) {
            const int t = tid + t4 * NTHR;                 // 32 e x 32 i4
            const int e = t >> 5, i4 = t & 31;
            const f32x4 v = ntload4(edge_attr + (size_t)(e0 + e) * FDIM + i4 * 4);
            const int f = i4 >> 3, j0 = (i4 & 1) * 4, qc = (i4 >> 1) & 3;
            const int g = e >> 4, lc = e & 15;
            bf16x4 bv = {(__bf16)v[0], (__bf16)v[1], (__bf16)v[2], (__bf16)v[3]};
            *(bf16x4*)(s_attr + (((f * 2 + g) * 64 + qc * 16 + lc) * 8 + j0)) = bv;
        }
        __syncthreads();   // B1

        // ---- phase 1: GEMM1 (wave w -> n-tiles 2w, 2w+1), h -> frag LDS ----
        {
            const int nt0 = w * 2;
            const float b1a = fc_b1[nt0 * 16 + li];
            const float b1b = fc_b1[(nt0 + 1) * 16 + li];
            bf16x8 A1[2][4];
            #pragma unroll
            for (int g = 0; g < 2; ++g)
                #pragma unroll
                for (int ks = 0; ks < 4; ++ks)
                    A1[g][ks] = *(const bf16x8*)(s_attr + ((ks * 2 + g) * 64 + lane) * 8);
            __syncthreads();   // B1.5: s_attr reads in regs -> s_h may overwrite
            #pragma unroll
            for (int nt2 = 0; nt2 < 2; ++nt2) {
                const int nt = nt0 + nt2;
                const float bias = nt2 ? b1b : b1a;
                bf16x8 Bf[4];
                #pragma unroll
                for (int ks = 0; ks < 4; ++ks)
                    Bf[ks] = *(const bf16x8*)(W1B + ((size_t)(nt * 4 + ks) * 64 + lane) * 8);
                f32x4 acc[2];
                #pragma unroll
                for (int g = 0; g < 2; ++g) acc[g] = (f32x4){bias, bias, bias, bias};
                #pragma unroll
                for (int ks = 0; ks < 4; ++ks)
                    #pragma unroll
                    for (int g = 0; g < 2; ++g) acc[g] = MFMA16(A1[g][ks], Bf[ks], acc[g]);
                const int f  = nt >> 1;
                const int qc = (2 * (nt & 1) + (li >> 3)) & 3;
                const int jb = li & 7;
                #pragma unroll
                for (int g = 0; g < 2; ++g)
                    #pragma unroll
                    for (int r = 0; r < 4; ++r)
                        s_h[((f * 2 + g) * 64 + qc * 16 + (quad * 4 + r)) * 8 + jb] =
                            (__bf16)fmaxf(acc[g][r], 0.f);
            }
        }
        __syncthreads();   // B2: h complete

        // ---- phase 2: A2 fragments (this wave's K-half) ----
        bf16x8 A2[2][2];   // [g][k2], global ks = kh*2 + k2
        #pragma unroll
        for (int g = 0; g < 2; ++g)
            #pragma unroll
            for (int k2 = 0; k2 < 2; ++k2)
                A2[g][k2] = *(const bf16x8*)(s_h + (((kh * 2 + k2) * 2 + g) * 64 + lane) * 8);

        // ---- phase 3: GEMM2 1-term + TP fold; depth-2 B prefetch ----
        f32x4 o0[2];       // p0 (th=0) or p3 (th=1)
        f32x4 o1[2][3];    // p1-t1 in [g][0] (th=0) or p2 (th=1)
        #pragma unroll
        for (int g = 0; g < 2; ++g) {
            o0[g] = (f32x4){0.f, 0.f, 0.f, 0.f};
            #pragma unroll
            for (int m = 0; m < 3; ++m) o1[g][m] = (f32x4){0.f, 0.f, 0.f, 0.f};
        }
        bf16x8 P[2][2];    // [stage][k2]; frag stride 512 bf16, tile stride 4*512
        #pragma unroll
        for (int s = 0; s < 2; ++s)
            #pragma unroll
            for (int k2 = 0; k2 < 2; ++k2)
                P[s][k2] = *(const bf16x8*)(Wp + (s * 4 + k2) * 512);

        #pragma unroll
        for (int half = 0; half < 2; ++half) {
            #pragma unroll
            for (int cc = 0; cc < 16; ++cc) {
                const int c = half * 16 + cc;
                const int u = cc;
                const bf16x8 b0 = P[c & 1][0];
                const bf16x8 b1 = P[c & 1][1];
                if (c + 2 < 32) {
                    #pragma unroll
                    for (int k2 = 0; k2 < 2; ++k2)
                        P[c & 1][k2] = *(const bf16x8*)(Wp + ((c + 2) * 4 + k2) * 512);
                }
                f32x4 acc[2];
                if (kh == 0) {
                    const float b2v = s_b2s[(tbase + c) * 16 + li];
                    acc[0] = (f32x4){b2v, b2v, b2v, b2v};
                    acc[1] = acc[0];
                } else {
                    acc[0] = (f32x4){0.f, 0.f, 0.f, 0.f};
                    acc[1] = acc[0];
                }
                #pragma unroll
                for (int g = 0; g < 2; ++g) {
                    acc[g] = MFMA16(A2[g][0], b0, acc[g]);
                    acc[g] = MFMA16(A2[g][1], b1, acc[g]);
                }
                // fold: p = th*2 + half (tile-constant)
                if (th == 0) {
                    if (half == 0) {
                        #pragma unroll
                        for (int g = 0; g < 2; ++g)
                            o0[g] += *(const f32x4*)&s_f[0][u][g * 16 + quad * 4] * acc[g];
                    } else {
                        #pragma unroll
                        for (int g = 0; g < 2; ++g)
                            o1[g][0] += *(const f32x4*)&s_f[1][u][g * 16 + quad * 4] * acc[g];
                    }
                } else {
                    if (half == 0) {
                        #pragma unroll
                        for (int g = 0; g < 2; ++g)
                            #pragma unroll
                            for (int m = 0; m < 3; ++m)
                                o1[g][m] += *(const f32x4*)&s_f[2 + m][u][g * 16 + quad * 4] * acc[g];
                    } else {
                        #pragma unroll
                        for (int g = 0; g < 2; ++g)
                            o0[g] += *(const f32x4*)&s_f[5][u][g * 16 + quad * 4] * acc[g];
                    }
                }
            }
        }
        if (th == 0) {   // expand t1 -> o1[m] = t1 * sh1[m] (order m=2,1,0)
            #pragma unroll
            for (int g = 0; g < 2; ++g) {
                const f32x4 t1 = o1[g][0];
                o1[g][2] = t1 * *(const f32x4*)&s_sh1[2][g * 16 + quad * 4];
                o1[g][1] = t1 * *(const f32x4*)&s_sh1[1][g * 16 + quad * 4];
                o1[g][0] = t1 * *(const f32x4*)&s_sh1[0][g * 16 + quad * 4];
            }
        }

        // ---- phase 4: pairwise merge in padded LDS; row-per-instr scatter ----
        float* zA = (float*)s_arena;            // [32][ZS] merged th=0
        float* zB = (float*)(s_arena + 8704);   // [32][ZS] merged th=1
        __syncthreads();   // B4: all s_f / s_attr / s_h readers done
        {
            float* zm = (th == 0) ? zA : zB;
            if (kh == 1) {             // kh1 waves init their th-area
                #pragma unroll
                for (int g = 0; g < 2; ++g)
                    #pragma unroll
                    for (int r = 0; r < 4; ++r) {
                        float* row = zm + (g * 16 + quad * 4 + r) * ZS;
                        row[li] = o0[g][r];
                        #pragma unroll
                        for (int m = 0; m < 3; ++m) row[16 + li * 3 + m] = o1[g][m][r];
                    }
            }
            __syncthreads();   // B5
            if (kh == 0) {             // kh0 waves fold their partial in (RMW)
                #pragma unroll
                for (int g = 0; g < 2; ++g)
                    #pragma unroll
                    for (int r = 0; r < 4; ++r) {
                        float* row = zm + (g * 16 + quad * 4 + r) * ZS;
                        row[li] += o0[g][r];
                        #pragma unroll
                        for (int m = 0; m < 3; ++m) row[16 + li * 3 + m] += o1[g][m][r];
                    }
            }
        }
        __syncthreads();   // B6: merge complete
        {
            // One edge row per atomic instruction: 64 contiguous floats = 4
            // fully-covered 64B lines. 8 edges per wave.
            const int ebase = w * 8;
            #pragma unroll
            for (int i = 0; i < 8; ++i) {
                const int e = ebase + i;
                const float v = zA[e * ZS + lane] + zB[e * ZS + lane];
                unsafeAtomicAdd(out_acc + (size_t)s_dst[e] * CDIM + lane, v);
            }
        }
    }
}

// ---------- finalize: float4-vectorized (G13) ----------
__global__ void finalize_kernel(const float* __restrict__ x,
                                const int*   __restrict__ cnt,
                                float*       __restrict__ out)
{
    const int i4 = blockIdx.x * blockDim.x + threadIdx.x;   // NODES*CDIM/4
    if (i4 < NODES * CDIM / 4) {
        const int n = i4 >> 4;                              // 16 float4 per node
        const int cv = cnt[n];
        const float rc = 1.0f / (float)(cv > 1 ? cv : 1);
        const f32x4 o  = ((const f32x4*)out)[i4];
        const f32x4 xv = ((const f32x4*)x)[i4];
        ((f32x4*)out)[i4] = o * rc + xv;
    }
}

extern "C" void kernel_launch(void* const* d_in, const int* in_sizes, int n_in,
                              void* d_out, int out_size, void* d_ws, size_t ws_size,
                              hipStream_t stream) {
    (void)in_sizes; (void)n_in; (void)out_size; (void)ws_size;
    const float* x          = (const float*)d_in[0];
    const int*   edge_index = (const int*)  d_in[1];
    const float* edge_attr  = (const float*)d_in[2];
    const float* edge_sh    = (const float*)d_in[3];
    const float* fc_w1      = (const float*)d_in[4];
    const float* fc_b1      = (const float*)d_in[5];
    const float* fc_w2      = (const float*)d_in[6];
    const float* fc_b2      = (const float*)d_in[7];
    float*  out = (float*)d_out;
    __bf16* W2B = (__bf16*)d_ws;
    __bf16* W1B = (__bf16*)((char*)d_ws + WS_W1B);
    int*    cnt = (int*)((char*)d_ws + WS_CNT);

    prep_kernel<<<256, NTHR, 0, stream>>>(fc_w1, fc_w2, W1B, W2B, out, cnt);
    fused_edge_kernel<<<NBLK, NTHR, 0, stream>>>(
        x, edge_index, edge_attr, edge_sh, fc_b1, fc_b2, W1B, W2B, out, cnt);
    finalize_kernel<<<(NODES * CDIM / 4 + NTHR - 1) / NTHR, NTHR, 0, stream>>>(x, cnt, out);
}

// Round 9
// 218.218 us; speedup vs baseline: 2.6359x; 2.6359x over previous
//
#include <hip/hip_runtime.h>
#include <stdint.h>

#define E_TOTAL 160000
#define NODES   10000
#define FDIM    128
#define HDIM    128
#define WN      1024
#define CDIM    64
#define EPB     32
#define NTHR    256

typedef __bf16 bf16x8 __attribute__((ext_vector_type(8)));
typedef __bf16 bf16x4 __attribute__((ext_vector_type(4)));
typedef float  f32x4  __attribute__((ext_vector_type(4)));

#define MFMA16(a,b,c) __builtin_amdgcn_mfma_f32_16x16x32_bf16(a,b,c,0,0,0)

// ws layout: [0, 256K) W2B bf16 B-frags ; [512K, 544K) W1B ; [576K, +40K) cnt
#define WS_W1B (512*1024)
#define WS_CNT (576*1024)

__device__ __forceinline__ f32x4 ntload4(const float* p) {
    return __builtin_nontemporal_load((const f32x4*)p);
}

// ---------- prep: W1/W2 -> bf16 B-fragments + zero out/cnt ----------
// Frag layout: [tile][ks][lane][8 bf16]; lane: n = tile*16+(lane&15), k = ks*32+(lane>>4)*8+j.
__global__ void prep_kernel(const float* __restrict__ W1, const float* __restrict__ W2,
                            __bf16* __restrict__ W1B, __bf16* __restrict__ W2B,
                            float* __restrict__ out_acc, int* __restrict__ cnt) {
    const int b   = blockIdx.x;
    const int tid = threadIdx.x;
    if (b < 72) {
        const float* W = (b < 64) ? W2 : W1;
        __bf16* outB   = (b < 64) ? W2B : W1B;
        const int N    = (b < 64) ? WN : HDIM;
        const int tile = (b < 64) ? b : (b - 64);
        const int lane = tid & 63, ks = tid >> 6;
        const int n  = tile * 16 + (lane & 15);
        const int k0 = ks * 32 + (lane >> 4) * 8;
        bf16x8 hi;
        #pragma unroll
        for (int j = 0; j < 8; ++j) hi[j] = (__bf16)W[(size_t)(k0 + j) * N + n];
        *(bf16x8*)(outB + ((size_t)(tile * 4 + ks) * 64 + lane) * 8) = hi;
    } else {
        const int zt     = (b - 72) * NTHR + tid;
        const int stride = ((int)gridDim.x - 72) * NTHR;
        const float4 z4 = make_float4(0.f, 0.f, 0.f, 0.f);
        for (int i = zt; i < NODES * CDIM / 4; i += stride) ((float4*)out_acc)[i] = z4;
        for (int i = zt; i < NODES; i += stride) cnt[i] = 0;
    }
}

// ---------- fused: gather + MLP + tensor product + scatter ----------
// EXACT round-3 kernel (proven 107.7 us fused / 222 us total) — byte-for-byte
// revert of r8's persistent-lite loop. Spill ledger (4 events): r1/r4 =
// min-waves>=5 cap; r6 = loop-carried prefetch regs; r8 = ANY loop wrapper
// around this body. The straight-line body sits at ~116/128 of its register
// envelope; it must stay straight-line with __launch_bounds__(256,4).
// Null ledger: r5 ILP depth-4; r7 B-frag reuse (0.5x L2 traffic, 0.5x
// barriers/edge). Structure is latency-bound at the register/occupancy
// corner; no remaining source-level lever moved it.
// 32 edges/block, 4 waves = (th = w>>1, kh = w&1).
// LDS arena 25152 B:
//   [0,8192)      s_attr == s_h (aliased; barrier B1.5 guards alias)
//   [8192,20480)  s_f [6][16][32] f32
//   [20480,24576) s_b2s
//   [24576,25008) s_sh1 [3][36]
//   [25024,25152) s_dst
//   tail: zA [0,8704), zB [8704,17408)  (ZS=68 rows; free after B4)
// Scatter: one FULL edge row (64 contiguous floats) per atomic instruction ->
// 4 fully-covered 64B lines/instr (r2->r3: WRITE_SIZE 325->45 MB, 3x time).
#define ZS 68
__global__ __launch_bounds__(NTHR, 4)
void fused_edge_kernel(const float* __restrict__ x,
                       const int*   __restrict__ edge_index,
                       const float* __restrict__ edge_attr,
                       const float* __restrict__ edge_sh,
                       const float* __restrict__ fc_b1,
                       const float* __restrict__ fc_b2,
                       const __bf16* __restrict__ W1B,
                       const __bf16* __restrict__ W2B,
                       float* __restrict__ out_acc,
                       int*   __restrict__ cnt)
{
    __shared__ __align__(16) char s_arena[25152];
    __bf16* s_attr = (__bf16*)s_arena;
    __bf16* s_h    = (__bf16*)s_arena;                 // aliased with s_attr
    float (*s_f)[16][32] = (float (*)[16][32])(s_arena + 8192);
    float*  s_b2s  = (float*)(s_arena + 20480);
    float (*s_sh1)[36] = (float (*)[36])(s_arena + 24576);
    int*    s_dst  = (int*)(s_arena + 25024);

    const int tid  = threadIdx.x;
    const int w    = tid >> 6;
    const int th   = w >> 1;
    const int kh   = w & 1;
    const int lane = tid & 63;
    const int quad = lane >> 4;
    const int li   = lane & 15;
    const int e0   = blockIdx.x * EPB;

    // ---- phase 0a: geometry factors (wave w, lanes<32: u in [w*4, w*4+4)) ----
    if (lane < 32) {
        const int e  = lane;
        const int up = w * 4;
        const int ge = e0 + e;
        const int src = edge_index[ge];
        const f32x4 sh4 = ntload4(edge_sh + (size_t)ge * 4);
        if (tid < EPB) {
            const int d = edge_index[E_TOTAL + ge];
            s_dst[e] = d;
            atomicAdd(&cnt[d], 1);
            s_sh1[0][e] = sh4.y; s_sh1[1][e] = sh4.z; s_sh1[2][e] = sh4.w;
        }
        const float* xp = x + (size_t)src * CDIM;
        const float4 x0v = *(const float4*)(xp + up);
        const float4 xa  = *(const float4*)(xp + 16 + up * 3);
        const float4 xb  = *(const float4*)(xp + 16 + up * 3 + 4);
        const float4 xc  = *(const float4*)(xp + 16 + up * 3 + 8);
        const float x1v[4][3] = {
            {xa.x, xa.y, xa.z}, {xa.w, xb.x, xb.y},
            {xb.z, xb.w, xc.x}, {xc.y, xc.z, xc.w}};
        const float x0a[4] = {x0v.x, x0v.y, x0v.z, x0v.w};
        const float alpha = 0.17677669529663689f;           // 1/sqrt(2*MUL)
        const float ai3   = alpha * 0.57735026918962576f;   // alpha/sqrt(3)
        const float sh0 = sh4.x;
        #pragma unroll
        for (int j = 0; j < 4; ++j) {
            const int u = up + j;
            const float x0u = x0a[j];
            s_f[0][u][e] = alpha * sh0 * x0u;
            s_f[1][u][e] = alpha * x0u;
            s_f[2][u][e] = alpha * sh0 * x1v[j][0];
            s_f[3][u][e] = alpha * sh0 * x1v[j][1];
            s_f[4][u][e] = alpha * sh0 * x1v[j][2];
            s_f[5][u][e] = ai3 * (x1v[j][0]*sh4.y + x1v[j][1]*sh4.z + x1v[j][2]*sh4.w);
        }
    }
    // ---- phase 0b: attr -> fragment-direct bf16 LDS; stage fc_b2 ----
    #pragma unroll
    for (int t4 = 0; t4 < 4; ++t4) {
        const int t = tid + t4 * NTHR;                 // 32 e x 32 i4
        const int e = t >> 5, i4 = t & 31;
        const f32x4 v = ntload4(edge_attr + (size_t)(e0 + e) * FDIM + i4 * 4);
        const int f = i4 >> 3, j0 = (i4 & 1) * 4, qc = (i4 >> 1) & 3;
        const int g = e >> 4, lc = e & 15;
        bf16x4 bv = {(__bf16)v[0], (__bf16)v[1], (__bf16)v[2], (__bf16)v[3]};
        *(bf16x4*)(s_attr + (((f * 2 + g) * 64 + qc * 16 + lc) * 8 + j0)) = bv;
    }
    *(f32x4*)&s_b2s[tid * 4] = *(const f32x4*)(fc_b2 + tid * 4);
    __syncthreads();   // B1

    // ---- phase 1: GEMM1 1-term (wave w -> n-tiles 2w, 2w+1), h -> frag bf16 LDS ----
    {
        const int nt0 = w * 2;
        const float b1a = fc_b1[nt0 * 16 + li];
        const float b1b = fc_b1[(nt0 + 1) * 16 + li];
        bf16x8 A1[2][4];
        #pragma unroll
        for (int g = 0; g < 2; ++g)
            #pragma unroll
            for (int ks = 0; ks < 4; ++ks)
                A1[g][ks] = *(const bf16x8*)(s_attr + ((ks * 2 + g) * 64 + lane) * 8);
        __syncthreads();   // B1.5: all s_attr reads in regs -> s_h may overwrite
        #pragma unroll
        for (int nt2 = 0; nt2 < 2; ++nt2) {
            const int nt = nt0 + nt2;
            const float bias = nt2 ? b1b : b1a;
            bf16x8 Bf[4];
            #pragma unroll
            for (int ks = 0; ks < 4; ++ks)
                Bf[ks] = *(const bf16x8*)(W1B + ((size_t)(nt * 4 + ks) * 64 + lane) * 8);
            f32x4 acc[2];
            #pragma unroll
            for (int g = 0; g < 2; ++g) acc[g] = (f32x4){bias, bias, bias, bias};
            #pragma unroll
            for (int ks = 0; ks < 4; ++ks)
                #pragma unroll
                for (int g = 0; g < 2; ++g) acc[g] = MFMA16(A1[g][ks], Bf[ks], acc[g]);
            const int f  = nt >> 1;
            const int qc = (2 * (nt & 1) + (li >> 3)) & 3;
            const int j  = li & 7;
            #pragma unroll
            for (int g = 0; g < 2; ++g)
                #pragma unroll
                for (int r = 0; r < 4; ++r)
                    s_h[((f * 2 + g) * 64 + qc * 16 + (quad * 4 + r)) * 8 + j] =
                        (__bf16)fmaxf(acc[g][r], 0.f);
        }
    }
    __syncthreads();   // B2: h complete

    // ---- phase 2: A2 fragments (this wave's K-half; zero VALU) ----
    bf16x8 A2[2][2];   // [g][k2], global ks = kh*2 + k2
    #pragma unroll
    for (int g = 0; g < 2; ++g)
        #pragma unroll
        for (int k2 = 0; k2 < 2; ++k2)
            A2[g][k2] = *(const bf16x8*)(s_h + (((kh * 2 + k2) * 2 + g) * 64 + lane) * 8);

    // ---- phase 3: GEMM2 1-term + TP fold; depth-2 B prefetch; b2 from LDS ----
    f32x4 o0[2];       // p0 (th=0) or p3 (th=1)
    f32x4 o1[2][3];    // p1-t1 in [g][0] (th=0) or p2 (th=1)
    #pragma unroll
    for (int g = 0; g < 2; ++g) {
        o0[g] = (f32x4){0.f, 0.f, 0.f, 0.f};
        #pragma unroll
        for (int m = 0; m < 3; ++m) o1[g][m] = (f32x4){0.f, 0.f, 0.f, 0.f};
    }
    const int tbase = th * 32;
    const __bf16* Wp = W2B + ((size_t)(tbase * 4 + kh * 2) * 64 + lane) * 8;
    bf16x8 P[2][2];    // [stage][k2]; frag stride 512 bf16, tile stride 4*512
    #pragma unroll
    for (int s = 0; s < 2; ++s)
        #pragma unroll
        for (int k2 = 0; k2 < 2; ++k2)
            P[s][k2] = *(const bf16x8*)(Wp + (s * 4 + k2) * 512);

    #pragma unroll
    for (int half = 0; half < 2; ++half) {
        #pragma unroll
        for (int cc = 0; cc < 16; ++cc) {
            const int c = half * 16 + cc;
            const int u = cc;
            const bf16x8 b0 = P[c & 1][0];
            const bf16x8 b1 = P[c & 1][1];
            if (c + 2 < 32) {
                #pragma unroll
                for (int k2 = 0; k2 < 2; ++k2)
                    P[c & 1][k2] = *(const bf16x8*)(Wp + ((c + 2) * 4 + k2) * 512);
            }
            f32x4 acc[2];
            if (kh == 0) {
                const float b2v = s_b2s[(tbase + c) * 16 + li];
                acc[0] = (f32x4){b2v, b2v, b2v, b2v};
                acc[1] = acc[0];
            } else {
                acc[0] = (f32x4){0.f, 0.f, 0.f, 0.f};
                acc[1] = acc[0];
            }
            #pragma unroll
            for (int g = 0; g < 2; ++g) {
                acc[g] = MFMA16(A2[g][0], b0, acc[g]);
                acc[g] = MFMA16(A2[g][1], b1, acc[g]);
            }
            // fold: p = th*2 + half (tile-constant)
            if (th == 0) {
                if (half == 0) {
                    #pragma unroll
                    for (int g = 0; g < 2; ++g)
                        o0[g] += *(const f32x4*)&s_f[0][u][g * 16 + quad * 4] * acc[g];
                } else {
                    #pragma unroll
                    for (int g = 0; g < 2; ++g)
                        o1[g][0] += *(const f32x4*)&s_f[1][u][g * 16 + quad * 4] * acc[g];
                }
            } else {
                if (half == 0) {
                    #pragma unroll
                    for (int g = 0; g < 2; ++g)
                        #pragma unroll
                        for (int m = 0; m < 3; ++m)
                            o1[g][m] += *(const f32x4*)&s_f[2 + m][u][g * 16 + quad * 4] * acc[g];
                } else {
                    #pragma unroll
                    for (int g = 0; g < 2; ++g)
                        o0[g] += *(const f32x4*)&s_f[5][u][g * 16 + quad * 4] * acc[g];
                }
            }
        }
    }
    if (th == 0) {   // expand t1 -> o1[m] = t1 * sh1[m] (order m=2,1,0)
        #pragma unroll
        for (int g = 0; g < 2; ++g) {
            const f32x4 t1 = o1[g][0];
            o1[g][2] = t1 * *(const f32x4*)&s_sh1[2][g * 16 + quad * 4];
            o1[g][1] = t1 * *(const f32x4*)&s_sh1[1][g * 16 + quad * 4];
            o1[g][0] = t1 * *(const f32x4*)&s_sh1[0][g * 16 + quad * 4];
        }
    }

    // ---- phase 4: pairwise merge in padded LDS areas; row-per-instr scatter ----
    float* zA = (float*)s_arena;            // [32][ZS] merged th=0 (overlaps attr)
    float* zB = (float*)(s_arena + 8704);   // [32][ZS] merged th=1 (overlaps s_f)
    __syncthreads();   // B4: all s_f / s_attr readers done
    {
        float* zm = (th == 0) ? zA : zB;
        if (kh == 1) {             // kh1 waves init their th-area with plain stores
            #pragma unroll
            for (int g = 0; g < 2; ++g)
                #pragma unroll
                for (int r = 0; r < 4; ++r) {
                    float* row = zm + (g * 16 + quad * 4 + r) * ZS;
                    row[li] = o0[g][r];
                    #pragma unroll
                    for (int m = 0; m < 3; ++m) row[16 + li * 3 + m] = o1[g][m][r];
                }
        }
        __syncthreads();   // B5
        if (kh == 0) {             // kh0 waves fold their partial in (RMW)
            #pragma unroll
            for (int g = 0; g < 2; ++g)
                #pragma unroll
                for (int r = 0; r < 4; ++r) {
                    float* row = zm + (g * 16 + quad * 4 + r) * ZS;
                    row[li] += o0[g][r];
                    #pragma unroll
                    for (int m = 0; m < 3; ++m) row[16 + li * 3 + m] += o1[g][m][r];
                }
        }
    }
    __syncthreads();   // B6: merge complete
    {
        // One edge row per atomic instruction: 64 contiguous floats = 4 full
        // 64B lines -> TCC merges to 4 line-ops/instr. 8 edges per wave.
        const int ebase = w * 8;
        #pragma unroll
        for (int i = 0; i < 8; ++i) {
            const int e = ebase + i;
            const float v = zA[e * ZS + lane] + zB[e * ZS + lane];
            unsafeAtomicAdd(out_acc + (size_t)s_dst[e] * CDIM + lane, v);
        }
    }
}

// ---------- finalize: float4-vectorized (G13; isolated from fused) ----------
__global__ void finalize_kernel(const float* __restrict__ x,
                                const int*   __restrict__ cnt,
                                float*       __restrict__ out)
{
    const int i4 = blockIdx.x * blockDim.x + threadIdx.x;   // NODES*CDIM/4
    if (i4 < NODES * CDIM / 4) {
        const int n = i4 >> 4;                              // 16 float4 per node
        const int cv = cnt[n];
        const float rc = 1.0f / (float)(cv > 1 ? cv : 1);
        const f32x4 o  = ((const f32x4*)out)[i4];
        const f32x4 xv = ((const f32x4*)x)[i4];
        ((f32x4*)out)[i4] = o * rc + xv;
    }
}

extern "C" void kernel_launch(void* const* d_in, const int* in_sizes, int n_in,
                              void* d_out, int out_size, void* d_ws, size_t ws_size,
                              hipStream_t stream) {
    (void)in_sizes; (void)n_in; (void)out_size; (void)ws_size;
    const float* x          = (const float*)d_in[0];
    const int*   edge_index = (const int*)  d_in[1];
    const float* edge_attr  = (const float*)d_in[2];
    const float* edge_sh    = (const float*)d_in[3];
    const float* fc_w1      = (const float*)d_in[4];
    const float* fc_b1      = (const float*)d_in[5];
    const float* fc_w2      = (const float*)d_in[6];
    const float* fc_b2      = (const float*)d_in[7];
    float*  out = (float*)d_out;
    __bf16* W2B = (__bf16*)d_ws;
    __bf16* W1B = (__bf16*)((char*)d_ws + WS_W1B);
    int*    cnt = (int*)((char*)d_ws + WS_CNT);

    prep_kernel<<<256, NTHR, 0, stream>>>(fc_w1, fc_w2, W1B, W2B, out, cnt);
    fused_edge_kernel<<<E_TOTAL / EPB, NTHR, 0, stream>>>(
        x, edge_index, edge_attr, edge_sh, fc_b1, fc_b2, W1B, W2B, out, cnt);
    finalize_kernel<<<(NODES * CDIM / 4 + NTHR - 1) / NTHR, NTHR, 0, stream>>>(x, cnt, out);
}

// Round 10
// 216.971 us; speedup vs baseline: 2.6510x; 1.0057x over previous
//
#include <hip/hip_runtime.h>
#include <stdint.h>

#define E_TOTAL 160000
#define NODES   10000
#define FDIM    128
#define HDIM    128
#define WN      1024
#define CDIM    64
#define EPB     64
#define NTHR    512
#define PTHR    256

typedef __bf16 bf16x8 __attribute__((ext_vector_type(8)));
typedef __bf16 bf16x4 __attribute__((ext_vector_type(4)));
typedef float  f32x4  __attribute__((ext_vector_type(4)));

#define MFMA16(a,b,c) __builtin_amdgcn_mfma_f32_16x16x32_bf16(a,b,c,0,0,0)

// ws layout: [0, 256K) W2B bf16 B-frags ; [512K, 544K) W1B ; [576K, +40K) cnt
#define WS_W1B (512*1024)
#define WS_CNT (576*1024)

__device__ __forceinline__ f32x4 ntload4(const float* p) {
    return __builtin_nontemporal_load((const f32x4*)p);
}

// ---------- prep: W1/W2 -> bf16 B-fragments + zero out/cnt ----------
// Frag layout: [tile][ks][lane][8 bf16]; lane: n = tile*16+(lane&15), k = ks*32+(lane>>4)*8+j.
__global__ void prep_kernel(const float* __restrict__ W1, const float* __restrict__ W2,
                            __bf16* __restrict__ W1B, __bf16* __restrict__ W2B,
                            float* __restrict__ out_acc, int* __restrict__ cnt) {
    const int b   = blockIdx.x;
    const int tid = threadIdx.x;
    if (b < 72) {
        const float* W = (b < 64) ? W2 : W1;
        __bf16* outB   = (b < 64) ? W2B : W1B;
        const int N    = (b < 64) ? WN : HDIM;
        const int tile = (b < 64) ? b : (b - 64);
        const int lane = tid & 63, ks = tid >> 6;
        const int n  = tile * 16 + (lane & 15);
        const int k0 = ks * 32 + (lane >> 4) * 8;
        bf16x8 hi;
        #pragma unroll
        for (int j = 0; j < 8; ++j) hi[j] = (__bf16)W[(size_t)(k0 + j) * N + n];
        *(bf16x8*)(outB + ((size_t)(tile * 4 + ks) * 64 + lane) * 8) = hi;
    } else {
        const int zt     = (b - 72) * PTHR + tid;
        const int stride = ((int)gridDim.x - 72) * PTHR;
        const float4 z4 = make_float4(0.f, 0.f, 0.f, 0.f);
        for (int i = zt; i < NODES * CDIM / 4; i += stride) ((float4*)out_acc)[i] = z4;
        for (int i = zt; i < NODES; i += stride) cnt[i] = 0;
    }
}

// ---------- fused: gather + MLP + tensor product + scatter ----------
// r4 structure, CORRECT register cap. 64 edges/block, 8 waves =
// (eh = w>>2 [edge half], th = (w>>1)&1 [tile half], kh = w&1 [K half]).
// r4 regressed ONLY because __launch_bounds__(512,6) capped VGPR at 85 and
// spilled (true footprint ~116 = 52 arch + ~64 acc). With (512,4) cap=128
// the footprint fits (r1/r4/r6/r8 spill ledger). Occupancy is then the
// register-THRESHOLD (116 <= 128 -> 16 waves/CU = 2 blocks x 8 waves),
// identical to r3/r9's 16 waves -- while W2B L2 traffic per edge and
// barriers per edge are both HALVED vs r3. This isolates the hypothesis
// that r7's traffic-halving null was an occupancy artifact (r7: 12 waves).
// LDS arena 46128 B:
//   [0,16384)      s_attr == s_h (aliased; barrier B1.5 guards alias)
//   [16384,40960)  s_f [6][16][64] f32
//   [40960,45056)  s_b2s
//   [45056,45872)  s_sh1 [3][68]
//   [45872,46128)  s_dst [64]
//   tail overlay:  zA [0,17408), zB [17408,34816)  (ZS=68 rows)
// Scatter: one FULL edge row (64 contiguous floats) per atomic instruction ->
// 4 fully-covered 64B lines/instr (proven r3: WRITE_SIZE 325->45 MB).
#define ZS 68
__global__ __launch_bounds__(NTHR, 4)
void fused_edge_kernel(const float* __restrict__ x,
                       const int*   __restrict__ edge_index,
                       const float* __restrict__ edge_attr,
                       const float* __restrict__ edge_sh,
                       const float* __restrict__ fc_b1,
                       const float* __restrict__ fc_b2,
                       const __bf16* __restrict__ W1B,
                       const __bf16* __restrict__ W2B,
                       float* __restrict__ out_acc,
                       int*   __restrict__ cnt)
{
    __shared__ __align__(16) char s_arena[46128];
    __bf16* s_attr = (__bf16*)s_arena;
    __bf16* s_h    = (__bf16*)s_arena;                 // aliased with s_attr
    float (*s_f)[16][64] = (float (*)[16][64])(s_arena + 16384);
    float*  s_b2s  = (float*)(s_arena + 40960);
    float (*s_sh1)[68] = (float (*)[68])(s_arena + 45056);
    int*    s_dst  = (int*)(s_arena + 45872);

    const int tid  = threadIdx.x;
    const int w    = tid >> 6;        // 0..7
    const int eh   = w >> 2;          // edge half (32 edges each)
    const int th   = (w >> 1) & 1;    // GEMM2 tile half
    const int kh   = w & 1;           // GEMM2 K half
    const int uq   = w & 3;           // phase-0a u-quarter / GEMM1 index
    const int lane = tid & 63;
    const int quad = lane >> 4;
    const int li   = lane & 15;
    const int e0   = blockIdx.x * EPB;
    const int eoff = eh * 32;

    // ---- phase 0a: geometry factors (wave (uq,eh), lanes<32) ----
    if (lane < 32) {
        const int e  = eoff + lane;       // 0..63 within block
        const int up = uq * 4;
        const int ge = e0 + e;
        const int src = edge_index[ge];
        const f32x4 sh4 = ntload4(edge_sh + (size_t)ge * 4);
        if (uq == 0) {
            const int d = edge_index[E_TOTAL + ge];
            s_dst[e] = d;
            atomicAdd(&cnt[d], 1);
            s_sh1[0][e] = sh4.y; s_sh1[1][e] = sh4.z; s_sh1[2][e] = sh4.w;
        }
        const float* xp = x + (size_t)src * CDIM;
        const float4 x0v = *(const float4*)(xp + up);
        const float4 xa  = *(const float4*)(xp + 16 + up * 3);
        const float4 xb  = *(const float4*)(xp + 16 + up * 3 + 4);
        const float4 xc  = *(const float4*)(xp + 16 + up * 3 + 8);
        const float x1v[4][3] = {
            {xa.x, xa.y, xa.z}, {xa.w, xb.x, xb.y},
            {xb.z, xb.w, xc.x}, {xc.y, xc.z, xc.w}};
        const float x0a[4] = {x0v.x, x0v.y, x0v.z, x0v.w};
        const float alpha = 0.17677669529663689f;           // 1/sqrt(2*MUL)
        const float ai3   = alpha * 0.57735026918962576f;   // alpha/sqrt(3)
        const float sh0 = sh4.x;
        #pragma unroll
        for (int j = 0; j < 4; ++j) {
            const int u = up + j;
            const float x0u = x0a[j];
            s_f[0][u][e] = alpha * sh0 * x0u;
            s_f[1][u][e] = alpha * x0u;
            s_f[2][u][e] = alpha * sh0 * x1v[j][0];
            s_f[3][u][e] = alpha * sh0 * x1v[j][1];
            s_f[4][u][e] = alpha * sh0 * x1v[j][2];
            s_f[5][u][e] = ai3 * (x1v[j][0]*sh4.y + x1v[j][1]*sh4.z + x1v[j][2]*sh4.w);
        }
    }
    // ---- phase 0b: attr -> fragment-direct bf16 LDS; stage fc_b2 ----
    // Frag layout: [f(=ks)][g(0..3)][lane][8] -> (((f*4+g)*64 + qc*16+lc)*8 + j0)
    #pragma unroll
    for (int t4 = 0; t4 < 4; ++t4) {
        const int t = tid + t4 * NTHR;                 // 64 e x 32 i4
        const int e = t >> 5, i4 = t & 31;
        const f32x4 v = ntload4(edge_attr + (size_t)(e0 + e) * FDIM + i4 * 4);
        const int f = i4 >> 3, j0 = (i4 & 1) * 4, qc = (i4 >> 1) & 3;
        const int g = e >> 4, lc = e & 15;
        bf16x4 bv = {(__bf16)v[0], (__bf16)v[1], (__bf16)v[2], (__bf16)v[3]};
        *(bf16x4*)(s_attr + (((f * 4 + g) * 64 + qc * 16 + lc) * 8 + j0)) = bv;
    }
    if (tid < 256) *(f32x4*)&s_b2s[tid * 4] = *(const f32x4*)(fc_b2 + tid * 4);
    __syncthreads();   // B1

    // ---- phase 1: GEMM1 (wave (eh,uq): n-tiles {2uq,2uq+1} x its half's g-pair) ----
    {
        const int gbase = eh * 2;
        bf16x8 A1[2][4];
        #pragma unroll
        for (int g2 = 0; g2 < 2; ++g2)
            #pragma unroll
            for (int ks = 0; ks < 4; ++ks)
                A1[g2][ks] = *(const bf16x8*)(s_attr + (((ks * 4 + gbase + g2) * 64 + lane) * 8));
        __syncthreads();   // B1.5: all s_attr reads in regs -> s_h may overwrite
        #pragma unroll
        for (int nt2 = 0; nt2 < 2; ++nt2) {
            const int nt = uq * 2 + nt2;
            const float bias = fc_b1[nt * 16 + li];
            bf16x8 Bf[4];
            #pragma unroll
            for (int ks = 0; ks < 4; ++ks)
                Bf[ks] = *(const bf16x8*)(W1B + ((size_t)(nt * 4 + ks) * 64 + lane) * 8);
            f32x4 acc[2];
            #pragma unroll
            for (int g2 = 0; g2 < 2; ++g2) acc[g2] = (f32x4){bias, bias, bias, bias};
            #pragma unroll
            for (int ks = 0; ks < 4; ++ks)
                #pragma unroll
                for (int g2 = 0; g2 < 2; ++g2) acc[g2] = MFMA16(A1[g2][ks], Bf[ks], acc[g2]);
            const int f  = uq;                         // nt>>1 == uq for both nt2
            const int qc = (2 * (nt & 1) + (li >> 3)) & 3;
            const int jb = li & 7;
            #pragma unroll
            for (int g2 = 0; g2 < 2; ++g2)
                #pragma unroll
                for (int r = 0; r < 4; ++r)
                    s_h[((f * 4 + gbase + g2) * 64 + qc * 16 + (quad * 4 + r)) * 8 + jb] =
                        (__bf16)fmaxf(acc[g2][r], 0.f);
        }
    }
    __syncthreads();   // B2: h complete

    // ---- phase 2: A2 fragments (this wave's K-half, its half's g-pair) ----
    bf16x8 A2[2][2];   // [g2][k2], global ks = kh*2 + k2
    #pragma unroll
    for (int g2 = 0; g2 < 2; ++g2)
        #pragma unroll
        for (int k2 = 0; k2 < 2; ++k2)
            A2[g2][k2] = *(const bf16x8*)(s_h + (((kh * 2 + k2) * 4 + eh * 2 + g2) * 64 + lane) * 8);

    // ---- phase 3: GEMM2 1-term + TP fold; depth-2 B prefetch; b2 from LDS ----
    f32x4 o0[2];       // p0 (th=0) or p3 (th=1)
    f32x4 o1[2][3];    // p1-t1 in [g2][0] (th=0) or p2 (th=1)
    #pragma unroll
    for (int g2 = 0; g2 < 2; ++g2) {
        o0[g2] = (f32x4){0.f, 0.f, 0.f, 0.f};
        #pragma unroll
        for (int m = 0; m < 3; ++m) o1[g2][m] = (f32x4){0.f, 0.f, 0.f, 0.f};
    }
    const int tbase = th * 32;
    const __bf16* Wp = W2B + ((size_t)(tbase * 4 + kh * 2) * 64 + lane) * 8;
    bf16x8 P[2][2];    // [stage][k2]; frag stride 512 bf16, tile stride 4*512
    #pragma unroll
    for (int s = 0; s < 2; ++s)
        #pragma unroll
        for (int k2 = 0; k2 < 2; ++k2)
            P[s][k2] = *(const bf16x8*)(Wp + (s * 4 + k2) * 512);

    #pragma unroll
    for (int half = 0; half < 2; ++half) {
        #pragma unroll
        for (int cc = 0; cc < 16; ++cc) {
            const int c = half * 16 + cc;
            const int u = cc;
            const bf16x8 b0 = P[c & 1][0];
            const bf16x8 b1 = P[c & 1][1];
            if (c + 2 < 32) {
                #pragma unroll
                for (int k2 = 0; k2 < 2; ++k2)
                    P[c & 1][k2] = *(const bf16x8*)(Wp + ((c + 2) * 4 + k2) * 512);
            }
            f32x4 acc[2];
            if (kh == 0) {
                const float b2v = s_b2s[(tbase + c) * 16 + li];
                acc[0] = (f32x4){b2v, b2v, b2v, b2v};
                acc[1] = acc[0];
            } else {
                acc[0] = (f32x4){0.f, 0.f, 0.f, 0.f};
                acc[1] = acc[0];
            }
            #pragma unroll
            for (int g2 = 0; g2 < 2; ++g2) {
                acc[g2] = MFMA16(A2[g2][0], b0, acc[g2]);
                acc[g2] = MFMA16(A2[g2][1], b1, acc[g2]);
            }
            // fold: p = th*2 + half (tile-constant)
            if (th == 0) {
                if (half == 0) {
                    #pragma unroll
                    for (int g2 = 0; g2 < 2; ++g2)
                        o0[g2] += *(const f32x4*)&s_f[0][u][eoff + g2 * 16 + quad * 4] * acc[g2];
                } else {
                    #pragma unroll
                    for (int g2 = 0; g2 < 2; ++g2)
                        o1[g2][0] += *(const f32x4*)&s_f[1][u][eoff + g2 * 16 + quad * 4] * acc[g2];
                }
            } else {
                if (half == 0) {
                    #pragma unroll
                    for (int g2 = 0; g2 < 2; ++g2)
                        #pragma unroll
                        for (int m = 0; m < 3; ++m)
                            o1[g2][m] += *(const f32x4*)&s_f[2 + m][u][eoff + g2 * 16 + quad * 4] * acc[g2];
                } else {
                    #pragma unroll
                    for (int g2 = 0; g2 < 2; ++g2)
                        o0[g2] += *(const f32x4*)&s_f[5][u][eoff + g2 * 16 + quad * 4] * acc[g2];
                }
            }
        }
    }
    if (th == 0) {   // expand t1 -> o1[m] = t1 * sh1[m] (order m=2,1,0)
        #pragma unroll
        for (int g2 = 0; g2 < 2; ++g2) {
            const f32x4 t1 = o1[g2][0];
            o1[g2][2] = t1 * *(const f32x4*)&s_sh1[2][eoff + g2 * 16 + quad * 4];
            o1[g2][1] = t1 * *(const f32x4*)&s_sh1[1][eoff + g2 * 16 + quad * 4];
            o1[g2][0] = t1 * *(const f32x4*)&s_sh1[0][eoff + g2 * 16 + quad * 4];
        }
    }

    // ---- phase 4: pairwise merge in padded LDS areas; row-per-instr scatter ----
    float* zA = (float*)s_arena;             // [64][ZS] merged th=0
    float* zB = (float*)(s_arena + 17408);   // [64][ZS] merged th=1
    __syncthreads();   // B4: all s_f / s_attr / s_h readers done
    {
        float* zm = (th == 0) ? zA : zB;
        if (kh == 1) {             // kh1 waves init their (th,eh) rows
            #pragma unroll
            for (int g2 = 0; g2 < 2; ++g2)
                #pragma unroll
                for (int r = 0; r < 4; ++r) {
                    float* row = zm + (eoff + g2 * 16 + quad * 4 + r) * ZS;
                    row[li] = o0[g2][r];
                    #pragma unroll
                    for (int m = 0; m < 3; ++m) row[16 + li * 3 + m] = o1[g2][m][r];
                }
        }
        __syncthreads();   // B5
        if (kh == 0) {             // kh0 waves fold their partial in (RMW)
            #pragma unroll
            for (int g2 = 0; g2 < 2; ++g2)
                #pragma unroll
                for (int r = 0; r < 4; ++r) {
                    float* row = zm + (eoff + g2 * 16 + quad * 4 + r) * ZS;
                    row[li] += o0[g2][r];
                    #pragma unroll
                    for (int m = 0; m < 3; ++m) row[16 + li * 3 + m] += o1[g2][m][r];
                }
        }
    }
    __syncthreads();   // B6: merge complete
    {
        // One edge row per atomic instruction: 64 contiguous floats = 4 full
        // 64B lines -> TCC merges to 4 line-ops/instr. 8 edges per wave.
        const int ebase = w * 8;
        #pragma unroll
        for (int i = 0; i < 8; ++i) {
            const int e = ebase + i;
            const float v = zA[e * ZS + lane] + zB[e * ZS + lane];
            unsafeAtomicAdd(out_acc + (size_t)s_dst[e] * CDIM + lane, v);
        }
    }
}

// ---------- finalize: float4-vectorized (G13; isolated from fused) ----------
__global__ void finalize_kernel(const float* __restrict__ x,
                                const int*   __restrict__ cnt,
                                float*       __restrict__ out)
{
    const int i4 = blockIdx.x * blockDim.x + threadIdx.x;   // NODES*CDIM/4
    if (i4 < NODES * CDIM / 4) {
        const int n = i4 >> 4;                              // 16 float4 per node
        const int cv = cnt[n];
        const float rc = 1.0f / (float)(cv > 1 ? cv : 1);
        const f32x4 o  = ((const f32x4*)out)[i4];
        const f32x4 xv = ((const f32x4*)x)[i4];
        ((f32x4*)out)[i4] = o * rc + xv;
    }
}

extern "C" void kernel_launch(void* const* d_in, const int* in_sizes, int n_in,
                              void* d_out, int out_size, void* d_ws, size_t ws_size,
                              hipStream_t stream) {
    (void)in_sizes; (void)n_in; (void)out_size; (void)ws_size;
    const float* x          = (const float*)d_in[0];
    const int*   edge_index = (const int*)  d_in[1];
    const float* edge_attr  = (const float*)d_in[2];
    const float* edge_sh    = (const float*)d_in[3];
    const float* fc_w1      = (const float*)d_in[4];
    const float* fc_b1      = (const float*)d_in[5];
    const float* fc_w2      = (const float*)d_in[6];
    const float* fc_b2      = (const float*)d_in[7];
    float*  out = (float*)d_out;
    __bf16* W2B = (__bf16*)d_ws;
    __bf16* W1B = (__bf16*)((char*)d_ws + WS_W1B);
    int*    cnt = (int*)((char*)d_ws + WS_CNT);

    prep_kernel<<<256, PTHR, 0, stream>>>(fc_w1, fc_w2, W1B, W2B, out, cnt);
    fused_edge_kernel<<<E_TOTAL / EPB, NTHR, 0, stream>>>(
        x, edge_index, edge_attr, edge_sh, fc_b1, fc_b2, W1B, W2B, out, cnt);
    finalize_kernel<<<(NODES * CDIM / 4 + PTHR - 1) / PTHR, PTHR, 0, stream>>>(x, cnt, out);
}

// Round 12
// 215.349 us; speedup vs baseline: 2.6710x; 1.0075x over previous
//
#include <hip/hip_runtime.h>
#include <stdint.h>

#define E_TOTAL 160000
#define NODES   10000
#define FDIM    128
#define HDIM    128
#define WN      1024
#define CDIM    64
#define EPB     64
#define NTHR    512
#define PTHR    256

typedef __bf16 bf16x8 __attribute__((ext_vector_type(8)));
typedef __bf16 bf16x4 __attribute__((ext_vector_type(4)));
typedef float  f32x4  __attribute__((ext_vector_type(4)));

#define MFMA16(a,b,c) __builtin_amdgcn_mfma_f32_16x16x32_bf16(a,b,c,0,0,0)

// ws layout: [0, 256K) W2B bf16 B-frags ; [512K, 544K) W1B ; [576K, +40K) cnt
#define WS_W1B (512*1024)
#define WS_CNT (576*1024)

__device__ __forceinline__ f32x4 ntload4(const float* p) {
    return __builtin_nontemporal_load((const f32x4*)p);
}

// ---------- prep: W1/W2 -> bf16 B-fragments + zero out/cnt ----------
// Frag layout: [tile][ks][lane][8 bf16]; lane: n = tile*16+(lane&15), k = ks*32+(lane>>4)*8+j.
__global__ void prep_kernel(const float* __restrict__ W1, const float* __restrict__ W2,
                            __bf16* __restrict__ W1B, __bf16* __restrict__ W2B,
                            float* __restrict__ out_acc, int* __restrict__ cnt) {
    const int b   = blockIdx.x;
    const int tid = threadIdx.x;
    if (b < 72) {
        const float* W = (b < 64) ? W2 : W1;
        __bf16* outB   = (b < 64) ? W2B : W1B;
        const int N    = (b < 64) ? WN : HDIM;
        const int tile = (b < 64) ? b : (b - 64);
        const int lane = tid & 63, ks = tid >> 6;
        const int n  = tile * 16 + (lane & 15);
        const int k0 = ks * 32 + (lane >> 4) * 8;
        bf16x8 hi;
        #pragma unroll
        for (int j = 0; j < 8; ++j) hi[j] = (__bf16)W[(size_t)(k0 + j) * N + n];
        *(bf16x8*)(outB + ((size_t)(tile * 4 + ks) * 64 + lane) * 8) = hi;
    } else {
        const int zt     = (b - 72) * PTHR + tid;
        const int stride = ((int)gridDim.x - 72) * PTHR;
        const float4 z4 = make_float4(0.f, 0.f, 0.f, 0.f);
        for (int i = zt; i < NODES * CDIM / 4; i += stride) ((float4*)out_acc)[i] = z4;
        for (int i = zt; i < NODES; i += stride) cnt[i] = 0;
    }
}

// ---------- fused: gather + MLP + tensor product + scatter ----------
// r10 structure (64 edges/block, 8 waves = (eh, th, kh), bounds(512,4),
// proven 105 us) MINUS two critical-path serializers:
//   1. s_h un-aliased from s_attr -> B1.5 deleted (was only an alias guard).
//   2. 4 merge zones (one per (th,kh) wave-pair) -> B5 + the whole
//      init-then-RMW LDS pass deleted; scatter sums 4 zones directly.
// Barriers 6 -> 4 (B1, B2, B4, B6). No new register state (VGPR must stay
// 52; FETCH/WRITE flat = spill tripwire per r1/r4/r6/r8 ledger).
// LDS map (69888 B -> 2 blocks/CU, same as r10's register-limited 2):
//   [0,16384)      s_attr
//   [16384,32768)  s_h
//   [32768,57344)  s_f [6][16][64] f32
//   [57344,61440)  s_b2s
//   [61440,62256)  s_sh1 [3][68]
//   zones overlay: [0,69632) = 4 x [64][ZS=68] f32  (all prior dead by B4)
//   [69632,69888)  s_dst [64]  (outside zones; live until scatter)
// Scatter: one FULL edge row (64 contiguous floats) per atomic instruction ->
// 4 fully-covered 64B lines/instr (proven r3: WRITE_SIZE 325->45 MB).
#define ZS 68
#define ZBYTES 17408
__global__ __launch_bounds__(NTHR, 4)
void fused_edge_kernel(const float* __restrict__ x,
                       const int*   __restrict__ edge_index,
                       const float* __restrict__ edge_attr,
                       const float* __restrict__ edge_sh,
                       const float* __restrict__ fc_b1,
                       const float* __restrict__ fc_b2,
                       const __bf16* __restrict__ W1B,
                       const __bf16* __restrict__ W2B,
                       float* __restrict__ out_acc,
                       int*   __restrict__ cnt)
{
    __shared__ __align__(16) char s_arena[69888];
    __bf16* s_attr = (__bf16*)s_arena;
    __bf16* s_h    = (__bf16*)(s_arena + 16384);       // NOT aliased (kills B1.5)
    float (*s_f)[16][64] = (float (*)[16][64])(s_arena + 32768);
    float*  s_b2s  = (float*)(s_arena + 57344);
    float (*s_sh1)[68] = (float (*)[68])(s_arena + 61440);
    int*    s_dst  = (int*)(s_arena + 69632);

    const int tid  = threadIdx.x;
    const int w    = tid >> 6;        // 0..7
    const int eh   = w >> 2;          // edge half (32 edges each)
    const int th   = (w >> 1) & 1;    // GEMM2 tile half
    const int kh   = w & 1;           // GEMM2 K half
    const int uq   = w & 3;           // phase-0a u-quarter / GEMM1 index
    const int lane = tid & 63;
    const int quad = lane >> 4;
    const int li   = lane & 15;
    const int e0   = blockIdx.x * EPB;
    const int eoff = eh * 32;

    // ---- phase 0a: geometry factors (wave (uq,eh), lanes<32) ----
    if (lane < 32) {
        const int e  = eoff + lane;       // 0..63 within block
        const int up = uq * 4;
        const int ge = e0 + e;
        const int src = edge_index[ge];
        const f32x4 sh4 = ntload4(edge_sh + (size_t)ge * 4);
        if (uq == 0) {
            const int d = edge_index[E_TOTAL + ge];
            s_dst[e] = d;
            atomicAdd(&cnt[d], 1);
            s_sh1[0][e] = sh4.y; s_sh1[1][e] = sh4.z; s_sh1[2][e] = sh4.w;
        }
        const float* xp = x + (size_t)src * CDIM;
        const float4 x0v = *(const float4*)(xp + up);
        const float4 xa  = *(const float4*)(xp + 16 + up * 3);
        const float4 xb  = *(const float4*)(xp + 16 + up * 3 + 4);
        const float4 xc  = *(const float4*)(xp + 16 + up * 3 + 8);
        const float x1v[4][3] = {
            {xa.x, xa.y, xa.z}, {xa.w, xb.x, xb.y},
            {xb.z, xb.w, xc.x}, {xc.y, xc.z, xc.w}};
        const float x0a[4] = {x0v.x, x0v.y, x0v.z, x0v.w};
        const float alpha = 0.17677669529663689f;           // 1/sqrt(2*MUL)
        const float ai3   = alpha * 0.57735026918962576f;   // alpha/sqrt(3)
        const float sh0 = sh4.x;
        #pragma unroll
        for (int j = 0; j < 4; ++j) {
            const int u = up + j;
            const float x0u = x0a[j];
            s_f[0][u][e] = alpha * sh0 * x0u;
            s_f[1][u][e] = alpha * x0u;
            s_f[2][u][e] = alpha * sh0 * x1v[j][0];
            s_f[3][u][e] = alpha * sh0 * x1v[j][1];
            s_f[4][u][e] = alpha * sh0 * x1v[j][2];
            s_f[5][u][e] = ai3 * (x1v[j][0]*sh4.y + x1v[j][1]*sh4.z + x1v[j][2]*sh4.w);
        }
    }
    // ---- phase 0b: attr -> fragment-direct bf16 LDS; stage fc_b2 ----
    // Frag layout: [f(=ks)][g(0..3)][lane][8] -> (((f*4+g)*64 + qc*16+lc)*8 + j0)
    #pragma unroll
    for (int t4 = 0; t4 < 4; ++t4) {
        const int t = tid + t4 * NTHR;                 // 64 e x 32 i4
        const int e = t >> 5, i4 = t & 31;
        const f32x4 v = ntload4(edge_attr + (size_t)(e0 + e) * FDIM + i4 * 4);
        const int f = i4 >> 3, j0 = (i4 & 1) * 4, qc = (i4 >> 1) & 3;
        const int g = e >> 4, lc = e & 15;
        bf16x4 bv = {(__bf16)v[0], (__bf16)v[1], (__bf16)v[2], (__bf16)v[3]};
        *(bf16x4*)(s_attr + (((f * 4 + g) * 64 + qc * 16 + lc) * 8 + j0)) = bv;
    }
    if (tid < 256) *(f32x4*)&s_b2s[tid * 4] = *(const f32x4*)(fc_b2 + tid * 4);
    __syncthreads();   // B1

    // ---- phase 1: GEMM1 (wave (eh,uq): n-tiles {2uq,2uq+1} x its half's g-pair) ----
    {
        const int gbase = eh * 2;
        bf16x8 A1[2][4];
        #pragma unroll
        for (int g2 = 0; g2 < 2; ++g2)
            #pragma unroll
            for (int ks = 0; ks < 4; ++ks)
                A1[g2][ks] = *(const bf16x8*)(s_attr + (((ks * 4 + gbase + g2) * 64 + lane) * 8));
        // no B1.5: s_h is a separate region now
        #pragma unroll
        for (int nt2 = 0; nt2 < 2; ++nt2) {
            const int nt = uq * 2 + nt2;
            const float bias = fc_b1[nt * 16 + li];
            bf16x8 Bf[4];
            #pragma unroll
            for (int ks = 0; ks < 4; ++ks)
                Bf[ks] = *(const bf16x8*)(W1B + ((size_t)(nt * 4 + ks) * 64 + lane) * 8);
            f32x4 acc[2];
            #pragma unroll
            for (int g2 = 0; g2 < 2; ++g2) acc[g2] = (f32x4){bias, bias, bias, bias};
            #pragma unroll
            for (int ks = 0; ks < 4; ++ks)
                #pragma unroll
                for (int g2 = 0; g2 < 2; ++g2) acc[g2] = MFMA16(A1[g2][ks], Bf[ks], acc[g2]);
            const int f  = uq;                         // nt>>1 == uq for both nt2
            const int qc = (2 * (nt & 1) + (li >> 3)) & 3;
            const int jb = li & 7;
            #pragma unroll
            for (int g2 = 0; g2 < 2; ++g2)
                #pragma unroll
                for (int r = 0; r < 4; ++r)
                    s_h[((f * 4 + gbase + g2) * 64 + qc * 16 + (quad * 4 + r)) * 8 + jb] =
                        (__bf16)fmaxf(acc[g2][r], 0.f);
        }
    }
    __syncthreads();   // B2: h complete

    // ---- phase 2: A2 fragments (this wave's K-half, its half's g-pair) ----
    bf16x8 A2[2][2];   // [g2][k2], global ks = kh*2 + k2
    #pragma unroll
    for (int g2 = 0; g2 < 2; ++g2)
        #pragma unroll
        for (int k2 = 0; k2 < 2; ++k2)
            A2[g2][k2] = *(const bf16x8*)(s_h + (((kh * 2 + k2) * 4 + eh * 2 + g2) * 64 + lane) * 8);

    // ---- phase 3: GEMM2 1-term + TP fold; depth-2 B prefetch; b2 from LDS ----
    f32x4 o0[2];       // p0 (th=0) or p3 (th=1)
    f32x4 o1[2][3];    // p1-t1 in [g2][0] (th=0) or p2 (th=1)
    #pragma unroll
    for (int g2 = 0; g2 < 2; ++g2) {
        o0[g2] = (f32x4){0.f, 0.f, 0.f, 0.f};
        #pragma unroll
        for (int m = 0; m < 3; ++m) o1[g2][m] = (f32x4){0.f, 0.f, 0.f, 0.f};
    }
    const int tbase = th * 32;
    const __bf16* Wp = W2B + ((size_t)(tbase * 4 + kh * 2) * 64 + lane) * 8;
    bf16x8 P[2][2];    // [stage][k2]; frag stride 512 bf16, tile stride 4*512
    #pragma unroll
    for (int s = 0; s < 2; ++s)
        #pragma unroll
        for (int k2 = 0; k2 < 2; ++k2)
            P[s][k2] = *(const bf16x8*)(Wp + (s * 4 + k2) * 512);

    #pragma unroll
    for (int half = 0; half < 2; ++half) {
        #pragma unroll
        for (int cc = 0; cc < 16; ++cc) {
            const int c = half * 16 + cc;
            const int u = cc;
            const bf16x8 b0 = P[c & 1][0];
            const bf16x8 b1 = P[c & 1][1];
            if (c + 2 < 32) {
                #pragma unroll
                for (int k2 = 0; k2 < 2; ++k2)
                    P[c & 1][k2] = *(const bf16x8*)(Wp + ((c + 2) * 4 + k2) * 512);
            }
            f32x4 acc[2];
            if (kh == 0) {
                const float b2v = s_b2s[(tbase + c) * 16 + li];
                acc[0] = (f32x4){b2v, b2v, b2v, b2v};
                acc[1] = acc[0];
            } else {
                acc[0] = (f32x4){0.f, 0.f, 0.f, 0.f};
                acc[1] = acc[0];
            }
            #pragma unroll
            for (int g2 = 0; g2 < 2; ++g2) {
                acc[g2] = MFMA16(A2[g2][0], b0, acc[g2]);
                acc[g2] = MFMA16(A2[g2][1], b1, acc[g2]);
            }
            // fold: p = th*2 + half (tile-constant)
            if (th == 0) {
                if (half == 0) {
                    #pragma unroll
                    for (int g2 = 0; g2 < 2; ++g2)
                        o0[g2] += *(const f32x4*)&s_f[0][u][eoff + g2 * 16 + quad * 4] * acc[g2];
                } else {
                    #pragma unroll
                    for (int g2 = 0; g2 < 2; ++g2)
                        o1[g2][0] += *(const f32x4*)&s_f[1][u][eoff + g2 * 16 + quad * 4] * acc[g2];
                }
            } else {
                if (half == 0) {
                    #pragma unroll
                    for (int g2 = 0; g2 < 2; ++g2)
                        #pragma unroll
                        for (int m = 0; m < 3; ++m)
                            o1[g2][m] += *(const f32x4*)&s_f[2 + m][u][eoff + g2 * 16 + quad * 4] * acc[g2];
                } else {
                    #pragma unroll
                    for (int g2 = 0; g2 < 2; ++g2)
                        o0[g2] += *(const f32x4*)&s_f[5][u][eoff + g2 * 16 + quad * 4] * acc[g2];
                }
            }
        }
    }
    if (th == 0) {   // expand t1 -> o1[m] = t1 * sh1[m] (order m=2,1,0)
        #pragma unroll
        for (int g2 = 0; g2 < 2; ++g2) {
            const f32x4 t1 = o1[g2][0];
            o1[g2][2] = t1 * *(const f32x4*)&s_sh1[2][eoff + g2 * 16 + quad * 4];
            o1[g2][1] = t1 * *(const f32x4*)&s_sh1[1][eoff + g2 * 16 + quad * 4];
            o1[g2][0] = t1 * *(const f32x4*)&s_sh1[0][eoff + g2 * 16 + quad * 4];
        }
    }

    // ---- phase 4: 4-zone dump (no RMW, no B5); row-per-instr scatter ----
    float* zone = (float*)(s_arena + (size_t)(th * 2 + kh) * ZBYTES);
    __syncthreads();   // B4: all s_attr/s_h/s_f/s_b2s/s_sh1 readers done
    {
        #pragma unroll
        for (int g2 = 0; g2 < 2; ++g2)
            #pragma unroll
            for (int r = 0; r < 4; ++r) {
                float* row = zone + (eoff + g2 * 16 + quad * 4 + r) * ZS;
                row[li] = o0[g2][r];
                #pragma unroll
                for (int m = 0; m < 3; ++m) row[16 + li * 3 + m] = o1[g2][m][r];
            }
    }
    __syncthreads();   // B6: all zones complete
    {
        // One edge row per atomic instruction: 64 contiguous floats = 4 full
        // 64B lines -> TCC merges to 4 line-ops/instr. 8 edges per wave.
        const float* z0 = (const float*)(s_arena);
        const float* z1 = (const float*)(s_arena + ZBYTES);
        const float* z2 = (const float*)(s_arena + 2 * ZBYTES);
        const float* z3 = (const float*)(s_arena + 3 * ZBYTES);
        const int ebase = w * 8;
        #pragma unroll
        for (int i = 0; i < 8; ++i) {
            const int e  = ebase + i;
            const int ix = e * ZS + lane;
            const float v = (z0[ix] + z1[ix]) + (z2[ix] + z3[ix]);
            unsafeAtomicAdd(out_acc + (size_t)s_dst[e] * CDIM + lane, v);
        }
    }
}

// ---------- finalize: float4-vectorized (G13; isolated from fused) ----------
__global__ void finalize_kernel(const float* __restrict__ x,
                                const int*   __restrict__ cnt,
                                float*       __restrict__ out)
{
    const int i4 = blockIdx.x * blockDim.x + threadIdx.x;   // NODES*CDIM/4
    if (i4 < NODES * CDIM / 4) {
        const int n = i4 >> 4;                              // 16 float4 per node
        const int cv = cnt[n];
        const float rc = 1.0f / (float)(cv > 1 ? cv : 1);
        const f32x4 o  = ((const f32x4*)out)[i4];
        const f32x4 xv = ((const f32x4*)x)[i4];
        ((f32x4*)out)[i4] = o * rc + xv;
    }
}

extern "C" void kernel_launch(void* const* d_in, const int* in_sizes, int n_in,
                              void* d_out, int out_size, void* d_ws, size_t ws_size,
                              hipStream_t stream) {
    (void)in_sizes; (void)n_in; (void)out_size; (void)ws_size;
    const float* x          = (const float*)d_in[0];
    const int*   edge_index = (const int*)  d_in[1];
    const float* edge_attr  = (const float*)d_in[2];
    const float* edge_sh    = (const float*)d_in[3];
    const float* fc_w1      = (const float*)d_in[4];
    const float* fc_b1      = (const float*)d_in[5];
    const float* fc_w2      = (const float*)d_in[6];
    const float* fc_b2      = (const float*)d_in[7];
    float*  out = (float*)d_out;
    __bf16* W2B = (__bf16*)d_ws;
    __bf16* W1B = (__bf16*)((char*)d_ws + WS_W1B);
    int*    cnt = (int*)((char*)d_ws + WS_CNT);

    prep_kernel<<<256, PTHR, 0, stream>>>(fc_w1, fc_w2, W1B, W2B, out, cnt);
    fused_edge_kernel<<<E_TOTAL / EPB, NTHR, 0, stream>>>(
        x, edge_index, edge_attr, edge_sh, fc_b1, fc_b2, W1B, W2B, out, cnt);
    finalize_kernel<<<(NODES * CDIM / 4 + PTHR - 1) / PTHR, PTHR, 0, stream>>>(x, cnt, out);
}